// Round 1
// baseline (589.636 us; speedup 1.0000x reference)
//
#include <hip/hip_runtime.h>
#include <hip/hip_bf16.h>
#include <math.h>

// Problem shape (SimpleGCN):
//   node_features [N=100000, 128] f32
//   edge_index    [2, E=1200000] i32   (row 0 = src, row 1 = dst)
//   post_mask     [P=50000] i32
//   W_enc [128,64] b_enc [64]  W_conv [64,64] b_conv [64]  W_out [64,1] b_out [1]
// out[p] = sigmoid( relu( (emb + segsum(emb[src]->dst))[post[p]] @ Wc + bc ) @ Wo + bo )

#define HIDDEN 64
#define NODE_DIM 128

// ---------------------------------------------------------------------------
// Stage 1: emb = relu(A @ W_enc + b_enc); also msg = emb (so the scatter kernel
// accumulates messages on top of emb, giving (emb + messages) directly).
// One wave per node; 64 lanes = 64 hidden outputs; W_enc staged in LDS.
// Node row held in 2 regs/lane, broadcast with __shfl (no intra-wave LDS sync).
// ---------------------------------------------------------------------------
__global__ __launch_bounds__(256) void k_encode(
    const float* __restrict__ A, const float* __restrict__ We,
    const float* __restrict__ be, float* __restrict__ emb,
    float* __restrict__ msg, int n_nodes)
{
    __shared__ float sW[NODE_DIM * HIDDEN];   // 32 KB
    const int tid = threadIdx.x;
    #pragma unroll
    for (int i = 0; i < (NODE_DIM * HIDDEN) / 256; ++i)
        sW[tid + i * 256] = We[tid + i * 256];
    const int lane = tid & 63;
    const int wave = tid >> 6;
    const float bias = be[lane];
    __syncthreads();

    const int n = blockIdx.x * 4 + wave;
    if (n >= n_nodes) return;

    const float* row = A + (size_t)n * NODE_DIM;
    const float a0 = row[lane];          // coalesced: lane i -> row[i]
    const float a1 = row[lane + 64];

    float acc = bias;
    #pragma unroll
    for (int k = 0; k < 64; ++k) {
        const float x0 = __shfl(a0, k);          // broadcast row[k]
        const float x1 = __shfl(a1, k);          // broadcast row[k+64]
        acc = fmaf(x0, sW[k * HIDDEN + lane], acc);          // banks: lane%32, 2-way (free)
        acc = fmaf(x1, sW[(k + 64) * HIDDEN + lane], acc);
    }
    const float h = fmaxf(acc, 0.0f);
    const size_t o = (size_t)n * HIDDEN + lane;
    emb[o] = h;
    msg[o] = h;   // init msg with emb so msg ends as emb + messages
}

// ---------------------------------------------------------------------------
// Stage 2: msg[dst] += emb[src] per edge. Wave per edge, lane per feature.
// src/dst loads are wave-uniform (scalar-load friendly); gather/atomic are
// 64-lane x 4 B = 256 B contiguous per edge. Table (25.6 MB) is L2/L3-resident.
// ---------------------------------------------------------------------------
__global__ __launch_bounds__(256) void k_scatter(
    const int* __restrict__ srcs, const int* __restrict__ dsts,
    const float* __restrict__ emb, float* __restrict__ msg, int n_edges)
{
    const int lane = threadIdx.x & 63;
    const int gw   = (blockIdx.x * 256 + threadIdx.x) >> 6;
    const int nw   = gridDim.x * 4;
    for (int e = gw; e < n_edges; e += nw) {
        const int s = srcs[e];
        const int d = dsts[e];
        const float v = emb[(size_t)s * HIDDEN + lane];
        atomicAdd(msg + (size_t)d * HIDDEN + lane, v);
    }
}

// ---------------------------------------------------------------------------
// Stage 3+4 fused, computed ONLY for posts (50k instead of 100k conv rows):
//   x = msg[post[p]]; h = relu(x @ Wc + bc); out[p] = sigmoid(dot(h, Wo) + bo)
// Wave per post; W_conv staged in LDS; x broadcast via __shfl; final dot via
// wave shuffle-reduction.
// ---------------------------------------------------------------------------
__global__ __launch_bounds__(256) void k_head(
    const int* __restrict__ post, const float* __restrict__ msg,
    const float* __restrict__ Wc, const float* __restrict__ bc,
    const float* __restrict__ Wo, const float* __restrict__ bo,
    float* __restrict__ out, int n_posts)
{
    __shared__ float sW[HIDDEN * HIDDEN];   // 16 KB
    const int tid = threadIdx.x;
    #pragma unroll
    for (int i = 0; i < (HIDDEN * HIDDEN) / 256; ++i)
        sW[tid + i * 256] = Wc[tid + i * 256];
    const int lane = tid & 63;
    const int wave = tid >> 6;
    const float bias = bc[lane];
    const float wo   = Wo[lane];
    const float bo_s = bo[0];
    __syncthreads();

    const int p = blockIdx.x * 4 + wave;
    if (p >= n_posts) return;

    const int n = post[p];
    const float x = msg[(size_t)n * HIDDEN + lane];   // 256 B coalesced gather

    float acc = bias;
    #pragma unroll
    for (int k = 0; k < 64; ++k) {
        const float xk = __shfl(x, k);
        acc = fmaf(xk, sW[k * HIDDEN + lane], acc);
    }
    const float h = fmaxf(acc, 0.0f);

    float contrib = h * wo;
    #pragma unroll
    for (int off = 32; off > 0; off >>= 1)
        contrib += __shfl_down(contrib, off);

    if (lane == 0) {
        const float z = contrib + bo_s;
        out[p] = 1.0f / (1.0f + __expf(-z));
    }
}

extern "C" void kernel_launch(void* const* d_in, const int* in_sizes, int n_in,
                              void* d_out, int out_size, void* d_ws, size_t ws_size,
                              hipStream_t stream) {
    const float* A    = (const float*)d_in[0];
    const int*   ei   = (const int*)  d_in[1];
    const int*   post = (const int*)  d_in[2];
    const float* We   = (const float*)d_in[3];
    const float* be   = (const float*)d_in[4];
    const float* Wc   = (const float*)d_in[5];
    const float* bc   = (const float*)d_in[6];
    const float* Wo   = (const float*)d_in[7];
    const float* bo   = (const float*)d_in[8];
    float* out = (float*)d_out;

    const int n_nodes = in_sizes[0] / NODE_DIM;   // 100000
    const int n_edges = in_sizes[1] / 2;          // 1200000
    const int n_posts = in_sizes[2];              // 50000

    // Workspace layout: emb [n_nodes*64] f32, msg [n_nodes*64] f32 (= 51.2 MB).
    // Both fully written by k_encode before any read -> poison-safe.
    float* emb = (float*)d_ws;
    float* msg = emb + (size_t)n_nodes * HIDDEN;

    const int* srcs = ei;
    const int* dsts = ei + n_edges;

    k_encode<<<(n_nodes + 3) / 4, 256, 0, stream>>>(A, We, be, emb, msg, n_nodes);
    k_scatter<<<4096, 256, 0, stream>>>(srcs, dsts, emb, msg, n_edges);
    k_head<<<(n_posts + 3) / 4, 256, 0, stream>>>(post, msg, Wc, bc, Wo, bo, out, n_posts);
}

// Round 2
// 497.429 us; speedup vs baseline: 1.1854x; 1.1854x over previous
//
#include <hip/hip_runtime.h>
#include <hip/hip_bf16.h>
#include <math.h>

// Problem shape (SimpleGCN):
//   node_features [N=100000, 128] f32
//   edge_index    [2, E=1200000] i32   (row 0 = src, row 1 = dst)
//   post_mask     [P=50000] i32
//   W_enc [128,64] b_enc [64]  W_conv [64,64] b_conv [64]  W_out [64,1] b_out [1]
// out[p] = sigmoid( relu( (emb + segsum(emb[src]->dst))[post[p]] @ Wc + bc ) @ Wo + bo )
//
// Key algorithmic fact: msg[] is only ever read at nodes in post_mask
// (~39.3% of nodes for 50k uniform draws over 100k). Scatter skips edges
// whose dst is not flagged -> ~60% of the atomic traffic eliminated.

#define HIDDEN 64
#define NODE_DIM 128

// ---------------------------------------------------------------------------
// Stage 1: emb = relu(A @ W_enc + b_enc); msg = emb (scatter accumulates on
// top, yielding emb+messages directly). Also zero the `needed` flag array
// (this kernel already visits every node; ws is poisoned 0xAA each call).
// ---------------------------------------------------------------------------
__global__ __launch_bounds__(256) void k_encode(
    const float* __restrict__ A, const float* __restrict__ We,
    const float* __restrict__ be, float* __restrict__ emb,
    float* __restrict__ msg, unsigned char* __restrict__ needed, int n_nodes)
{
    __shared__ float sW[NODE_DIM * HIDDEN];   // 32 KB
    const int tid = threadIdx.x;
    #pragma unroll
    for (int i = 0; i < (NODE_DIM * HIDDEN) / 256; ++i)
        sW[tid + i * 256] = We[tid + i * 256];
    const int lane = tid & 63;
    const int wave = tid >> 6;
    const float bias = be[lane];
    __syncthreads();

    const int n = blockIdx.x * 4 + wave;
    if (n >= n_nodes) return;
    if (lane == 0) needed[n] = 0;

    const float* row = A + (size_t)n * NODE_DIM;
    const float a0 = row[lane];          // coalesced: lane i -> row[i]
    const float a1 = row[lane + 64];

    float acc = bias;
    #pragma unroll
    for (int k = 0; k < 64; ++k) {
        const float x0 = __shfl(a0, k);          // broadcast row[k]
        const float x1 = __shfl(a1, k);          // broadcast row[k+64]
        acc = fmaf(x0, sW[k * HIDDEN + lane], acc);          // banks: lane%32, 2-way (free)
        acc = fmaf(x1, sW[(k + 64) * HIDDEN + lane], acc);
    }
    const float h = fmaxf(acc, 0.0f);
    const size_t o = (size_t)n * HIDDEN + lane;
    emb[o] = h;
    msg[o] = h;   // init msg with emb so msg ends as emb + messages
}

// ---------------------------------------------------------------------------
// Flag the nodes whose msg[] is actually read downstream.
// ---------------------------------------------------------------------------
__global__ __launch_bounds__(256) void k_setflags(
    const int* __restrict__ post, unsigned char* __restrict__ needed, int n_posts)
{
    const int p = blockIdx.x * 256 + threadIdx.x;
    if (p < n_posts) needed[post[p]] = 1;
}

// ---------------------------------------------------------------------------
// Stage 2: msg[dst] += emb[src] per edge, ONLY for flagged dst (~39.3%).
// Wave per edge, lane per feature. dst/flag loads are wave-uniform broadcast;
// gather/atomic are 64-lane x 4 B = 256 B contiguous per edge.
// ---------------------------------------------------------------------------
__global__ __launch_bounds__(256) void k_scatter(
    const int* __restrict__ srcs, const int* __restrict__ dsts,
    const unsigned char* __restrict__ needed,
    const float* __restrict__ emb, float* __restrict__ msg, int n_edges)
{
    const int lane = threadIdx.x & 63;
    const int gw   = (blockIdx.x * 256 + threadIdx.x) >> 6;
    const int nw   = gridDim.x * 4;
    for (int e = gw; e < n_edges; e += nw) {
        const int d = dsts[e];
        if (!needed[d]) continue;          // wave-uniform branch, ~60% skipped
        const int s = srcs[e];
        const float v = emb[(size_t)s * HIDDEN + lane];
        atomicAdd(msg + (size_t)d * HIDDEN + lane, v);
    }
}

// ---------------------------------------------------------------------------
// Stage 3+4 fused, computed ONLY for posts (50k instead of 100k conv rows):
//   x = msg[post[p]]; h = relu(x @ Wc + bc); out[p] = sigmoid(dot(h, Wo) + bo)
// ---------------------------------------------------------------------------
__global__ __launch_bounds__(256) void k_head(
    const int* __restrict__ post, const float* __restrict__ msg,
    const float* __restrict__ Wc, const float* __restrict__ bc,
    const float* __restrict__ Wo, const float* __restrict__ bo,
    float* __restrict__ out, int n_posts)
{
    __shared__ float sW[HIDDEN * HIDDEN];   // 16 KB
    const int tid = threadIdx.x;
    #pragma unroll
    for (int i = 0; i < (HIDDEN * HIDDEN) / 256; ++i)
        sW[tid + i * 256] = Wc[tid + i * 256];
    const int lane = tid & 63;
    const int wave = tid >> 6;
    const float bias = bc[lane];
    const float wo   = Wo[lane];
    const float bo_s = bo[0];
    __syncthreads();

    const int p = blockIdx.x * 4 + wave;
    if (p >= n_posts) return;

    const int n = post[p];
    const float x = msg[(size_t)n * HIDDEN + lane];   // 256 B coalesced gather

    float acc = bias;
    #pragma unroll
    for (int k = 0; k < 64; ++k) {
        const float xk = __shfl(x, k);
        acc = fmaf(xk, sW[k * HIDDEN + lane], acc);
    }
    const float h = fmaxf(acc, 0.0f);

    float contrib = h * wo;
    #pragma unroll
    for (int off = 32; off > 0; off >>= 1)
        contrib += __shfl_down(contrib, off);

    if (lane == 0) {
        const float z = contrib + bo_s;
        out[p] = 1.0f / (1.0f + __expf(-z));
    }
}

extern "C" void kernel_launch(void* const* d_in, const int* in_sizes, int n_in,
                              void* d_out, int out_size, void* d_ws, size_t ws_size,
                              hipStream_t stream) {
    const float* A    = (const float*)d_in[0];
    const int*   ei   = (const int*)  d_in[1];
    const int*   post = (const int*)  d_in[2];
    const float* We   = (const float*)d_in[3];
    const float* be   = (const float*)d_in[4];
    const float* Wc   = (const float*)d_in[5];
    const float* bc   = (const float*)d_in[6];
    const float* Wo   = (const float*)d_in[7];
    const float* bo   = (const float*)d_in[8];
    float* out = (float*)d_out;

    const int n_nodes = in_sizes[0] / NODE_DIM;   // 100000
    const int n_edges = in_sizes[1] / 2;          // 1200000
    const int n_posts = in_sizes[2];              // 50000

    // Workspace layout: emb [n_nodes*64] f32, msg [n_nodes*64] f32 (51.2 MB),
    // needed [n_nodes] u8. All bytes written before read -> poison-safe.
    float* emb = (float*)d_ws;
    float* msg = emb + (size_t)n_nodes * HIDDEN;
    unsigned char* needed = (unsigned char*)(msg + (size_t)n_nodes * HIDDEN);

    const int* srcs = ei;
    const int* dsts = ei + n_edges;

    k_encode<<<(n_nodes + 3) / 4, 256, 0, stream>>>(A, We, be, emb, msg, needed, n_nodes);
    k_setflags<<<(n_posts + 255) / 256, 256, 0, stream>>>(post, needed, n_posts);
    k_scatter<<<4096, 256, 0, stream>>>(srcs, dsts, needed, emb, msg, n_edges);
    k_head<<<(n_posts + 3) / 4, 256, 0, stream>>>(post, msg, Wc, bc, Wo, bo, out, n_posts);
}

// Round 3
// 371.329 us; speedup vs baseline: 1.5879x; 1.3396x over previous
//
#include <hip/hip_runtime.h>
#include <hip/hip_bf16.h>
#include <math.h>

// Problem shape (SimpleGCN):
//   node_features [N=100000, 128] f32
//   edge_index    [2, E=1200000] i32   (row 0 = src, row 1 = dst)
//   post_mask     [P=50000] i32
//   W_enc [128,64] b_enc [64]  W_conv [64,64] b_conv [64]  W_out [64,1] b_out [1]
// out[p] = sigmoid( relu( (emb + segsum(emb[src]->dst))[post[p]] @ Wc + bc ) @ Wo + bo )
//
// Round-2 lesson: the __shfl-broadcast GEMV was DS-pipe bound (encode 205 us,
// VALUBusy 14%). This version holds the weight column per-lane in VGPRs and
// makes the activation row WAVE-UNIFORM (1 wave per block) so its loads are
// scalar (s_load) -> inner loop is pure v_fmac. No LDS, no shuffles.

#define HIDDEN 64
#define NODE_DIM 128

// ---------------------------------------------------------------------------
// Stage 1: emb = relu(A @ W_enc + b_enc) for all nodes; msg = emb only for
// `needed` nodes (scatter accumulates on top -> emb+messages).
// One wave per block; lane j owns W_enc column j in 128 VGPRs; grid-stride
// over nodes amortizes the weight staging.
// ---------------------------------------------------------------------------
__global__ __launch_bounds__(64) void k_encode(
    const float* __restrict__ A, const float* __restrict__ We,
    const float* __restrict__ be, const unsigned char* __restrict__ needed,
    float* __restrict__ emb, float* __restrict__ msg, int n_nodes)
{
    const int lane = threadIdx.x;
    float w[NODE_DIM];                       // We[k][lane], coalesced loads
    #pragma unroll
    for (int k = 0; k < NODE_DIM; ++k) w[k] = We[k * HIDDEN + lane];
    const float bias = be[lane];

    for (int n = blockIdx.x; n < n_nodes; n += gridDim.x) {
        // n is wave-uniform -> row loads compile to scalar loads
        const float4* __restrict__ row = (const float4*)(A + (size_t)n * NODE_DIM);
        float acc0 = 0.f, acc1 = 0.f, acc2 = 0.f, acc3 = 0.f;
        #pragma unroll
        for (int k4 = 0; k4 < NODE_DIM / 4; ++k4) {
            const float4 a = row[k4];
            acc0 = fmaf(a.x, w[4 * k4 + 0], acc0);
            acc1 = fmaf(a.y, w[4 * k4 + 1], acc1);
            acc2 = fmaf(a.z, w[4 * k4 + 2], acc2);
            acc3 = fmaf(a.w, w[4 * k4 + 3], acc3);
        }
        const float h = fmaxf((acc0 + acc1) + (acc2 + acc3) + bias, 0.0f);
        const size_t o = (size_t)n * HIDDEN + lane;
        emb[o] = h;
        if (needed[n]) msg[o] = h;           // wave-uniform branch, ~39% taken
    }
}

// ---------------------------------------------------------------------------
// Flag the nodes whose msg[] is actually read downstream (~39.3% of nodes).
// ---------------------------------------------------------------------------
__global__ __launch_bounds__(256) void k_setflags(
    const int* __restrict__ post, unsigned char* __restrict__ needed, int n_posts)
{
    const int p = blockIdx.x * 256 + threadIdx.x;
    if (p < n_posts) needed[post[p]] = 1;
}

// ---------------------------------------------------------------------------
// Stage 2: msg[dst] += emb[src] per edge, ONLY for flagged dst.
// Wave per edge, lane per feature; 256 B gather + 256 B atomic per kept edge.
// ---------------------------------------------------------------------------
__global__ __launch_bounds__(256) void k_scatter(
    const int* __restrict__ srcs, const int* __restrict__ dsts,
    const unsigned char* __restrict__ needed,
    const float* __restrict__ emb, float* __restrict__ msg, int n_edges)
{
    const int lane = threadIdx.x & 63;
    const int gw   = (blockIdx.x * 256 + threadIdx.x) >> 6;
    const int nw   = gridDim.x * 4;
    for (int e = gw; e < n_edges; e += nw) {
        const int d = dsts[e];
        if (!needed[d]) continue;            // ~60% of edges skipped
        const int s = srcs[e];
        const float v = emb[(size_t)s * HIDDEN + lane];
        atomicAdd(msg + (size_t)d * HIDDEN + lane, v);
    }
}

// ---------------------------------------------------------------------------
// Stage 3+4 fused, posts only:
//   x = msg[post[p]]; h = relu(x @ Wc + bc); out[p] = sigmoid(dot(h, Wo) + bo)
// Same VGPR-weights + uniform-row-scalar-load structure as k_encode.
// ---------------------------------------------------------------------------
__global__ __launch_bounds__(64) void k_head(
    const int* __restrict__ post, const float* __restrict__ msg,
    const float* __restrict__ Wc, const float* __restrict__ bc,
    const float* __restrict__ Wo, const float* __restrict__ bo,
    float* __restrict__ out, int n_posts)
{
    const int lane = threadIdx.x;
    float w[HIDDEN];                         // Wc[k][lane]
    #pragma unroll
    for (int k = 0; k < HIDDEN; ++k) w[k] = Wc[k * HIDDEN + lane];
    const float bias = bc[lane];
    const float wo   = Wo[lane];
    const float bo_s = bo[0];

    for (int p = blockIdx.x; p < n_posts; p += gridDim.x) {
        const int n = post[p];               // p uniform -> n uniform
        const float4* __restrict__ row = (const float4*)(msg + (size_t)n * HIDDEN);
        float acc0 = 0.f, acc1 = 0.f, acc2 = 0.f, acc3 = 0.f;
        #pragma unroll
        for (int k4 = 0; k4 < HIDDEN / 4; ++k4) {
            const float4 a = row[k4];
            acc0 = fmaf(a.x, w[4 * k4 + 0], acc0);
            acc1 = fmaf(a.y, w[4 * k4 + 1], acc1);
            acc2 = fmaf(a.z, w[4 * k4 + 2], acc2);
            acc3 = fmaf(a.w, w[4 * k4 + 3], acc3);
        }
        const float h = fmaxf((acc0 + acc1) + (acc2 + acc3) + bias, 0.0f);

        float c = h * wo;
        #pragma unroll
        for (int off = 32; off > 0; off >>= 1)
            c += __shfl_down(c, off);
        if (lane == 0)
            out[p] = 1.0f / (1.0f + __expf(-(c + bo_s)));
    }
}

extern "C" void kernel_launch(void* const* d_in, const int* in_sizes, int n_in,
                              void* d_out, int out_size, void* d_ws, size_t ws_size,
                              hipStream_t stream) {
    const float* A    = (const float*)d_in[0];
    const int*   ei   = (const int*)  d_in[1];
    const int*   post = (const int*)  d_in[2];
    const float* We   = (const float*)d_in[3];
    const float* be   = (const float*)d_in[4];
    const float* Wc   = (const float*)d_in[5];
    const float* bc   = (const float*)d_in[6];
    const float* Wo   = (const float*)d_in[7];
    const float* bo   = (const float*)d_in[8];
    float* out = (float*)d_out;

    const int n_nodes = in_sizes[0] / NODE_DIM;   // 100000
    const int n_edges = in_sizes[1] / 2;          // 1200000
    const int n_posts = in_sizes[2];              // 50000

    // Workspace: emb [n_nodes*64] f32, msg [n_nodes*64] f32, needed [n_nodes] u8.
    // emb fully written; msg rows only for flagged nodes (the only rows read);
    // needed memset to 0 each call -> poison-safe.
    float* emb = (float*)d_ws;
    float* msg = emb + (size_t)n_nodes * HIDDEN;
    unsigned char* needed = (unsigned char*)(msg + (size_t)n_nodes * HIDDEN);

    const int* srcs = ei;
    const int* dsts = ei + n_edges;

    hipMemsetAsync(needed, 0, n_nodes, stream);
    k_setflags<<<(n_posts + 255) / 256, 256, 0, stream>>>(post, needed, n_posts);
    k_encode<<<8192, 64, 0, stream>>>(A, We, be, needed, emb, msg, n_nodes);
    k_scatter<<<4096, 256, 0, stream>>>(srcs, dsts, needed, emb, msg, n_edges);
    k_head<<<4096, 64, 0, stream>>>(post, msg, Wc, bc, Wo, bo, out, n_posts);
}

// Round 4
// 320.031 us; speedup vs baseline: 1.8424x; 1.1603x over previous
//
#include <hip/hip_runtime.h>
#include <hip/hip_bf16.h>
#include <math.h>

// Problem shape (SimpleGCN):
//   node_features [N=100000, 128] f32
//   edge_index    [2, E=1200000] i32   (row 0 = src, row 1 = dst)
//   post_mask     [P=50000] i32
//   W_enc [128,64] b_enc [64]  W_conv [64,64] b_conv [64]  W_out [64,1] b_out [1]
// out[p] = sigmoid( relu( (emb + segsum(emb[src]->dst))[post[p]] @ Wc + bc ) @ Wo + bo )
//
// Round-3 lesson: fp32 atomicAdd scatter is L2-atomic bound and write-throughs
// every 256 B line to HBM per edge (WRITE_SIZE 118 MB at 164 us). This version
// builds an exact CSR (count -> scan -> fill) over edges whose dst is flagged
// (~39.3% of nodes are ever read), then gathers per flagged node with zero
// atomics, writing each output row exactly once into a COMPACTED msg buffer.

#define HIDDEN 64
#define NODE_DIM 128
#define SCAN_CHUNK 1024   // 256 threads x 4 elements per scan block

// ---------------------------------------------------------------------------
// Flag + compact the nodes whose msg is read downstream. flag[] must be 0,
// listCnt 0 (memset). Winner of CAS appends to nodelist and records inv[n].
// ---------------------------------------------------------------------------
__global__ __launch_bounds__(256) void k_setflags(
    const int* __restrict__ post, int* __restrict__ flag,
    int* __restrict__ nodelist, int* __restrict__ inv,
    int* __restrict__ listCnt, int n_posts)
{
    const int p = blockIdx.x * 256 + threadIdx.x;
    if (p >= n_posts) return;
    const int n = post[p];
    if (atomicCAS(&flag[n], 0, 1) == 0) {
        const int i = atomicAdd(listCnt, 1);
        nodelist[i] = n;
        inv[n] = i;
    }
}

// ---------------------------------------------------------------------------
// Stage 1: emb = relu(A @ W_enc + b_enc). Lane j owns W_enc column j in
// 128 VGPRs; node row is wave-uniform -> scalar loads; inner loop pure v_fmac.
// ---------------------------------------------------------------------------
__global__ __launch_bounds__(64) void k_encode(
    const float* __restrict__ A, const float* __restrict__ We,
    const float* __restrict__ be, float* __restrict__ emb, int n_nodes)
{
    const int lane = threadIdx.x;
    float w[NODE_DIM];
    #pragma unroll
    for (int k = 0; k < NODE_DIM; ++k) w[k] = We[k * HIDDEN + lane];
    const float bias = be[lane];

    for (int n = blockIdx.x; n < n_nodes; n += gridDim.x) {
        const float4* __restrict__ row = (const float4*)(A + (size_t)n * NODE_DIM);
        float acc0 = 0.f, acc1 = 0.f, acc2 = 0.f, acc3 = 0.f;
        #pragma unroll
        for (int k4 = 0; k4 < NODE_DIM / 4; ++k4) {
            const float4 a = row[k4];
            acc0 = fmaf(a.x, w[4 * k4 + 0], acc0);
            acc1 = fmaf(a.y, w[4 * k4 + 1], acc1);
            acc2 = fmaf(a.z, w[4 * k4 + 2], acc2);
            acc3 = fmaf(a.w, w[4 * k4 + 3], acc3);
        }
        emb[(size_t)n * HIDDEN + lane] = fmaxf((acc0 + acc1) + (acc2 + acc3) + bias, 0.0f);
    }
}

// ---------------------------------------------------------------------------
// CSR step 1: in-degree count per flagged destination. counts pre-zeroed.
// ---------------------------------------------------------------------------
__global__ __launch_bounds__(256) void k_count(
    const int* __restrict__ dsts, const int* __restrict__ flag,
    int* __restrict__ count, int n_edges)
{
    const int stride = gridDim.x * 256;
    for (int e = blockIdx.x * 256 + threadIdx.x; e < n_edges; e += stride) {
        const int d = dsts[e];
        if (flag[d]) atomicAdd(&count[d], 1);
    }
}

// ---------------------------------------------------------------------------
// CSR step 2a: per-1024-chunk exclusive scan of count into row_start (local),
// chunk totals into blockSums.
// ---------------------------------------------------------------------------
__global__ __launch_bounds__(256) void k_scan1(
    const int* __restrict__ count, int* __restrict__ row_start,
    int* __restrict__ blockSums, int n)
{
    __shared__ int s[256];
    const int tid = threadIdx.x;
    const int base = blockIdx.x * SCAN_CHUNK + tid * 4;
    int c0 = (base + 0 < n) ? count[base + 0] : 0;
    int c1 = (base + 1 < n) ? count[base + 1] : 0;
    int c2 = (base + 2 < n) ? count[base + 2] : 0;
    int c3 = (base + 3 < n) ? count[base + 3] : 0;
    const int t = c0 + c1 + c2 + c3;
    s[tid] = t;
    __syncthreads();
    #pragma unroll
    for (int off = 1; off < 256; off <<= 1) {
        int v = (tid >= off) ? s[tid - off] : 0;
        __syncthreads();
        s[tid] += v;
        __syncthreads();
    }
    int run = s[tid] - t;              // exclusive base for this thread
    if (base + 0 < n) row_start[base + 0] = run;           run += c0;
    if (base + 1 < n) row_start[base + 1] = run;           run += c1;
    if (base + 2 < n) row_start[base + 2] = run;           run += c2;
    if (base + 3 < n) row_start[base + 3] = run;
    if (tid == 255) blockSums[blockIdx.x] = s[255];
}

// ---------------------------------------------------------------------------
// CSR step 2b: exclusive scan of chunk totals (nb <= 128).
// ---------------------------------------------------------------------------
__global__ __launch_bounds__(128) void k_scan2(
    const int* __restrict__ blockSums, int* __restrict__ blockBase, int nb)
{
    __shared__ int s[128];
    const int tid = threadIdx.x;
    const int v0 = (tid < nb) ? blockSums[tid] : 0;
    s[tid] = v0;
    __syncthreads();
    #pragma unroll
    for (int off = 1; off < 128; off <<= 1) {
        int v = (tid >= off) ? s[tid - off] : 0;
        __syncthreads();
        s[tid] += v;
        __syncthreads();
    }
    blockBase[tid] = s[tid] - v0;
}

// ---------------------------------------------------------------------------
// CSR step 2c: add chunk bases; init fill cursor.
// ---------------------------------------------------------------------------
__global__ __launch_bounds__(256) void k_scan3(
    int* __restrict__ row_start, const int* __restrict__ blockBase,
    int* __restrict__ cursor, int n)
{
    const int i = blockIdx.x * 256 + threadIdx.x;
    if (i >= n) return;
    const int r = row_start[i] + blockBase[i / SCAN_CHUNK];
    row_start[i] = r;
    cursor[i] = r;
}

// ---------------------------------------------------------------------------
// CSR step 3: fill slot lists (src ids) for flagged destinations.
// ---------------------------------------------------------------------------
__global__ __launch_bounds__(256) void k_fill(
    const int* __restrict__ srcs, const int* __restrict__ dsts,
    const int* __restrict__ flag, int* __restrict__ cursor,
    int* __restrict__ slots, int n_edges)
{
    const int stride = gridDim.x * 256;
    for (int e = blockIdx.x * 256 + threadIdx.x; e < n_edges; e += stride) {
        const int d = dsts[e];
        if (!flag[d]) continue;
        const int idx = atomicAdd(&cursor[d], 1);
        slots[idx] = srcs[e];
    }
}

// ---------------------------------------------------------------------------
// Gather: one wave per flagged node. acc = emb[n] + sum(emb[src]) over its
// in-edges; write ONE compacted row, no atomics. 4-wide manual unroll for MLP.
// ---------------------------------------------------------------------------
__global__ __launch_bounds__(256) void k_gather(
    const int* __restrict__ nodelist, const int* __restrict__ listCnt,
    const int* __restrict__ row_start, const int* __restrict__ count,
    const int* __restrict__ slots, const float* __restrict__ emb,
    float* __restrict__ msg_c)
{
    const int lane = threadIdx.x & 63;
    const int gw   = (blockIdx.x * 256 + threadIdx.x) >> 6;
    const int nw   = gridDim.x * 4;
    const int nc   = listCnt[0];
    for (int i = gw; i < nc; i += nw) {
        const int n    = nodelist[i];
        const int base = row_start[n];
        const int m    = count[n];
        float acc = emb[(size_t)n * HIDDEN + lane];
        int c = 0;
        for (; c + 3 < m; c += 4) {                 // 4 gathers in flight
            const int s0 = slots[base + c + 0];
            const int s1 = slots[base + c + 1];
            const int s2 = slots[base + c + 2];
            const int s3 = slots[base + c + 3];
            const float v0 = emb[(size_t)s0 * HIDDEN + lane];
            const float v1 = emb[(size_t)s1 * HIDDEN + lane];
            const float v2 = emb[(size_t)s2 * HIDDEN + lane];
            const float v3 = emb[(size_t)s3 * HIDDEN + lane];
            acc += (v0 + v1) + (v2 + v3);
        }
        for (; c < m; ++c)
            acc += emb[(size_t)slots[base + c] * HIDDEN + lane];
        msg_c[(size_t)i * HIDDEN + lane] = acc;
    }
}

// ---------------------------------------------------------------------------
// Head: x = msg_c[inv[post[p]]]; h = relu(x @ Wc + bc); out = sigmoid(h.Wo+bo)
// ---------------------------------------------------------------------------
__global__ __launch_bounds__(64) void k_head(
    const int* __restrict__ post, const int* __restrict__ inv,
    const float* __restrict__ msg_c,
    const float* __restrict__ Wc, const float* __restrict__ bc,
    const float* __restrict__ Wo, const float* __restrict__ bo,
    float* __restrict__ out, int n_posts)
{
    const int lane = threadIdx.x;
    float w[HIDDEN];
    #pragma unroll
    for (int k = 0; k < HIDDEN; ++k) w[k] = Wc[k * HIDDEN + lane];
    const float bias = bc[lane];
    const float wo   = Wo[lane];
    const float bo_s = bo[0];

    for (int p = blockIdx.x; p < n_posts; p += gridDim.x) {
        const int n = post[p];               // uniform
        const int i = inv[n];                // uniform
        const float4* __restrict__ row = (const float4*)(msg_c + (size_t)i * HIDDEN);
        float acc0 = 0.f, acc1 = 0.f, acc2 = 0.f, acc3 = 0.f;
        #pragma unroll
        for (int k4 = 0; k4 < HIDDEN / 4; ++k4) {
            const float4 a = row[k4];
            acc0 = fmaf(a.x, w[4 * k4 + 0], acc0);
            acc1 = fmaf(a.y, w[4 * k4 + 1], acc1);
            acc2 = fmaf(a.z, w[4 * k4 + 2], acc2);
            acc3 = fmaf(a.w, w[4 * k4 + 3], acc3);
        }
        const float h = fmaxf((acc0 + acc1) + (acc2 + acc3) + bias, 0.0f);

        float c = h * wo;
        #pragma unroll
        for (int off = 32; off > 0; off >>= 1)
            c += __shfl_down(c, off);
        if (lane == 0)
            out[p] = 1.0f / (1.0f + __expf(-(c + bo_s)));
    }
}

extern "C" void kernel_launch(void* const* d_in, const int* in_sizes, int n_in,
                              void* d_out, int out_size, void* d_ws, size_t ws_size,
                              hipStream_t stream) {
    const float* A    = (const float*)d_in[0];
    const int*   ei   = (const int*)  d_in[1];
    const int*   post = (const int*)  d_in[2];
    const float* We   = (const float*)d_in[3];
    const float* be   = (const float*)d_in[4];
    const float* Wc   = (const float*)d_in[5];
    const float* bc   = (const float*)d_in[6];
    const float* Wo   = (const float*)d_in[7];
    const float* bo   = (const float*)d_in[8];
    float* out = (float*)d_out;

    const int n_nodes = in_sizes[0] / NODE_DIM;   // 100000
    const int n_edges = in_sizes[1] / 2;          // 1200000
    const int n_posts = in_sizes[2];              // 50000

    // ---- workspace layout (all regions written before read; ~45.7 MB) ----
    char* p = (char*)d_ws;
    float* emb      = (float*)p;              p += (size_t)n_nodes * HIDDEN * 4;  // 25.6 MB
    float* msg_c    = (float*)p;              p += (size_t)n_posts * HIDDEN * 4;  // 12.8 MB (compacted)
    int*   slots    = (int*)p;                p += (size_t)n_edges * 4;           // 4.8 MB
    int*   flag     = (int*)p;                p += (size_t)n_nodes * 4;           // zeroed
    int*   count    = (int*)p;                p += (size_t)n_nodes * 4;           // zeroed
    int*   listCnt  = (int*)p;                p += 256;                           // zeroed
    int*   row_start= (int*)p;                p += (size_t)n_nodes * 4;
    int*   cursor   = (int*)p;                p += (size_t)n_nodes * 4;
    int*   nodelist = (int*)p;                p += (size_t)n_nodes * 4;
    int*   inv      = (int*)p;                p += (size_t)n_nodes * 4;
    int*   blockSums= (int*)p;                p += 512;
    int*   blockBase= (int*)p;                p += 512;

    const int* srcs = ei;
    const int* dsts = ei + n_edges;
    const int nb = (n_nodes + SCAN_CHUNK - 1) / SCAN_CHUNK;   // 98 <= 128

    // flag, count, listCnt are contiguous -> single memset
    hipMemsetAsync(flag, 0, (size_t)n_nodes * 8 + 256, stream);
    k_setflags<<<(n_posts + 255) / 256, 256, 0, stream>>>(post, flag, nodelist, inv, listCnt, n_posts);
    k_encode<<<8192, 64, 0, stream>>>(A, We, be, emb, n_nodes);
    k_count<<<4096, 256, 0, stream>>>(dsts, flag, count, n_edges);
    k_scan1<<<nb, 256, 0, stream>>>(count, row_start, blockSums, n_nodes);
    k_scan2<<<1, 128, 0, stream>>>(blockSums, blockBase, nb);
    k_scan3<<<(n_nodes + 255) / 256, 256, 0, stream>>>(row_start, blockBase, cursor, n_nodes);
    k_fill<<<4096, 256, 0, stream>>>(srcs, dsts, flag, cursor, slots, n_edges);
    k_gather<<<6144, 256, 0, stream>>>(nodelist, listCnt, row_start, count, slots, emb, msg_c);
    k_head<<<4096, 64, 0, stream>>>(post, inv, msg_c, Wc, bc, Wo, bo, out, n_posts);
}

// Round 5
// 233.719 us; speedup vs baseline: 2.5228x; 1.3693x over previous
//
#include <hip/hip_runtime.h>
#include <hip/hip_bf16.h>
#include <math.h>

// Problem shape (SimpleGCN):
//   node_features [N=100000, 128] f32
//   edge_index    [2, E=1200000] i32   (row 0 = src, row 1 = dst)
//   post_mask     [P=50000] i32
//   W_enc [128,64] b_enc [64]  W_conv [64,64] b_conv [64]  W_out [64,1] b_out [1]
// out[p] = sigmoid( relu( (emb + segsum(emb[src]->dst))[post[p]] @ Wc + bc ) @ Wo + bo )
//
// Round-4 lesson: the "VGPR-resident weights" encode never materialized —
// compiler allocated 68 VGPRs and re-loaded W per node (latency-bound,
// 120+ us at 9% VALU). Encode is GEMM-shaped -> MFMA (16x16x32 bf16):
// one wave = 16-node M-tile, W fragments built once per wave (64 VGPRs),
// A loaded fp32 + packed-cvt to bf16, fp32 accumulate. ~17 us memory floor.

#define HIDDEN 64
#define NODE_DIM 128
#define SCAN_CHUNK 1024   // 256 threads x 4 elements per scan block

typedef __attribute__((ext_vector_type(8))) short short8;   // 8 bf16 (4 VGPR)
typedef __attribute__((ext_vector_type(4))) float floatx4;  // mfma C/D frag

union F2B { short8 s; __hip_bfloat162 h[4]; };

__device__ inline short8 cvt8(const float4& p, const float4& q) {
    F2B u;
    u.h[0] = __float22bfloat162_rn(make_float2(p.x, p.y));
    u.h[1] = __float22bfloat162_rn(make_float2(p.z, p.w));
    u.h[2] = __float22bfloat162_rn(make_float2(q.x, q.y));
    u.h[3] = __float22bfloat162_rn(make_float2(q.z, q.w));
    return u.s;
}

// ---------------------------------------------------------------------------
// Stage 1 (MFMA): emb = relu(A @ W_enc + b_enc).
// Wave handles a 16-node M-tile: 4 k-steps x 4 n-tiles of 16x16x32 bf16 mfma.
// A-frag: lane holds A[m=lane&15][k = ks*32 + (lane>>4)*8 + j] (j=0..7)
// B-frag: lane holds We[k][n = nt*16 + (lane&15)], same k mapping.
// D: row=(lane>>4)*4+reg, col=lane&15  ->  node = t*16+row, ch = nt*16+col.
// ---------------------------------------------------------------------------
__global__ __launch_bounds__(256) void k_encode_mfma(
    const float* __restrict__ A, const float* __restrict__ We,
    const float* __restrict__ be, float* __restrict__ emb, int n_tiles)
{
    const int lane = threadIdx.x & 63;
    const int r    = lane & 15;
    const int quad = lane >> 4;

    // Build B fragments once per wave (We is 32 KB, L1/L2-resident).
    short8 Wb[4][4];   // [kstep][ntile] -> 64 VGPRs persistent
    #pragma unroll
    for (int ks = 0; ks < 4; ++ks) {
        #pragma unroll
        for (int nt = 0; nt < 4; ++nt) {
            F2B u;
            #pragma unroll
            for (int jj = 0; jj < 4; ++jj) {
                const int k0 = ks * 32 + quad * 8 + 2 * jj;
                const float lo = We[(size_t)k0 * HIDDEN + nt * 16 + r];
                const float hi = We[(size_t)(k0 + 1) * HIDDEN + nt * 16 + r];
                u.h[jj] = __float22bfloat162_rn(make_float2(lo, hi));
            }
            Wb[ks][nt] = u.s;
        }
    }
    float bias[4];
    #pragma unroll
    for (int nt = 0; nt < 4; ++nt) bias[nt] = be[nt * 16 + r];

    const int wid    = (blockIdx.x * 256 + threadIdx.x) >> 6;
    const int nwaves = gridDim.x * 4;
    for (int t = wid; t < n_tiles; t += nwaves) {
        const float* Arow = A + (size_t)t * 16 * NODE_DIM + (size_t)r * NODE_DIM + quad * 8;
        float4 a[4][2];
        #pragma unroll
        for (int ks = 0; ks < 4; ++ks) {             // 8 independent 16B loads
            a[ks][0] = *(const float4*)(Arow + ks * 32);
            a[ks][1] = *(const float4*)(Arow + ks * 32 + 4);
        }
        floatx4 acc[4] = {};
        #pragma unroll
        for (int ks = 0; ks < 4; ++ks) {
            const short8 af = cvt8(a[ks][0], a[ks][1]);
            #pragma unroll
            for (int nt = 0; nt < 4; ++nt)
                acc[nt] = __builtin_amdgcn_mfma_f32_16x16x32_bf16(af, Wb[ks][nt], acc[nt], 0, 0, 0);
        }
        #pragma unroll
        for (int nt = 0; nt < 4; ++nt) {
            #pragma unroll
            for (int g = 0; g < 4; ++g) {
                const int node = t * 16 + quad * 4 + g;
                const float h = fmaxf(acc[nt][g] + bias[nt], 0.0f);
                emb[(size_t)node * HIDDEN + nt * 16 + r] = h;
            }
        }
    }
}

// Tail nodes (n_nodes % 16) — one wave per node, plain vector path.
__global__ __launch_bounds__(64) void k_encode_tail(
    const float* __restrict__ A, const float* __restrict__ We,
    const float* __restrict__ be, float* __restrict__ emb, int base)
{
    const int lane = threadIdx.x;
    const int n = base + blockIdx.x;
    const float* row = A + (size_t)n * NODE_DIM;
    float acc = be[lane];
    for (int k = 0; k < NODE_DIM; ++k)
        acc = fmaf(row[k], We[(size_t)k * HIDDEN + lane], acc);
    emb[(size_t)n * HIDDEN + lane] = fmaxf(acc, 0.0f);
}

// ---------------------------------------------------------------------------
// Flag + compact the nodes whose msg is read downstream (~39.3% of nodes).
// ---------------------------------------------------------------------------
__global__ __launch_bounds__(256) void k_setflags(
    const int* __restrict__ post, int* __restrict__ flag,
    int* __restrict__ nodelist, int* __restrict__ inv,
    int* __restrict__ listCnt, int n_posts)
{
    const int p = blockIdx.x * 256 + threadIdx.x;
    if (p >= n_posts) return;
    const int n = post[p];
    if (atomicCAS(&flag[n], 0, 1) == 0) {
        const int i = atomicAdd(listCnt, 1);
        nodelist[i] = n;
        inv[n] = i;
    }
}

// CSR step 1: in-degree count per flagged destination.
__global__ __launch_bounds__(256) void k_count(
    const int* __restrict__ dsts, const int* __restrict__ flag,
    int* __restrict__ count, int n_edges)
{
    const int stride = gridDim.x * 256;
    for (int e = blockIdx.x * 256 + threadIdx.x; e < n_edges; e += stride) {
        const int d = dsts[e];
        if (flag[d]) atomicAdd(&count[d], 1);
    }
}

// CSR step 2a: per-1024-chunk exclusive scan; chunk totals out.
__global__ __launch_bounds__(256) void k_scan1(
    const int* __restrict__ count, int* __restrict__ row_start,
    int* __restrict__ blockSums, int n)
{
    __shared__ int s[256];
    const int tid = threadIdx.x;
    const int base = blockIdx.x * SCAN_CHUNK + tid * 4;
    int c0 = (base + 0 < n) ? count[base + 0] : 0;
    int c1 = (base + 1 < n) ? count[base + 1] : 0;
    int c2 = (base + 2 < n) ? count[base + 2] : 0;
    int c3 = (base + 3 < n) ? count[base + 3] : 0;
    const int t = c0 + c1 + c2 + c3;
    s[tid] = t;
    __syncthreads();
    #pragma unroll
    for (int off = 1; off < 256; off <<= 1) {
        int v = (tid >= off) ? s[tid - off] : 0;
        __syncthreads();
        s[tid] += v;
        __syncthreads();
    }
    int run = s[tid] - t;
    if (base + 0 < n) row_start[base + 0] = run;           run += c0;
    if (base + 1 < n) row_start[base + 1] = run;           run += c1;
    if (base + 2 < n) row_start[base + 2] = run;           run += c2;
    if (base + 3 < n) row_start[base + 3] = run;
    if (tid == 255) blockSums[blockIdx.x] = s[255];
}

// CSR step 2b: exclusive scan of chunk totals (nb <= 128).
__global__ __launch_bounds__(128) void k_scan2(
    const int* __restrict__ blockSums, int* __restrict__ blockBase, int nb)
{
    __shared__ int s[128];
    const int tid = threadIdx.x;
    const int v0 = (tid < nb) ? blockSums[tid] : 0;
    s[tid] = v0;
    __syncthreads();
    #pragma unroll
    for (int off = 1; off < 128; off <<= 1) {
        int v = (tid >= off) ? s[tid - off] : 0;
        __syncthreads();
        s[tid] += v;
        __syncthreads();
    }
    blockBase[tid] = s[tid] - v0;
}

// CSR step 2c: add chunk bases; init fill cursor.
__global__ __launch_bounds__(256) void k_scan3(
    int* __restrict__ row_start, const int* __restrict__ blockBase,
    int* __restrict__ cursor, int n)
{
    const int i = blockIdx.x * 256 + threadIdx.x;
    if (i >= n) return;
    const int r = row_start[i] + blockBase[i / SCAN_CHUNK];
    row_start[i] = r;
    cursor[i] = r;
}

// CSR step 3: fill slot lists (src ids) for flagged destinations.
__global__ __launch_bounds__(256) void k_fill(
    const int* __restrict__ srcs, const int* __restrict__ dsts,
    const int* __restrict__ flag, int* __restrict__ cursor,
    int* __restrict__ slots, int n_edges)
{
    const int stride = gridDim.x * 256;
    for (int e = blockIdx.x * 256 + threadIdx.x; e < n_edges; e += stride) {
        const int d = dsts[e];
        if (!flag[d]) continue;
        const int idx = atomicAdd(&cursor[d], 1);
        slots[idx] = srcs[e];
    }
}

// ---------------------------------------------------------------------------
// Gather: one wave per flagged node; sum emb rows of its in-edges; one
// non-atomic compacted row write.
// ---------------------------------------------------------------------------
__global__ __launch_bounds__(256) void k_gather(
    const int* __restrict__ nodelist, const int* __restrict__ listCnt,
    const int* __restrict__ row_start, const int* __restrict__ count,
    const int* __restrict__ slots, const float* __restrict__ emb,
    float* __restrict__ msg_c)
{
    const int lane = threadIdx.x & 63;
    const int gw   = (blockIdx.x * 256 + threadIdx.x) >> 6;
    const int nw   = gridDim.x * 4;
    const int nc   = listCnt[0];
    for (int i = gw; i < nc; i += nw) {
        const int n    = nodelist[i];
        const int base = row_start[n];
        const int m    = count[n];
        float acc = emb[(size_t)n * HIDDEN + lane];
        int c = 0;
        for (; c + 3 < m; c += 4) {
            const int s0 = slots[base + c + 0];
            const int s1 = slots[base + c + 1];
            const int s2 = slots[base + c + 2];
            const int s3 = slots[base + c + 3];
            const float v0 = emb[(size_t)s0 * HIDDEN + lane];
            const float v1 = emb[(size_t)s1 * HIDDEN + lane];
            const float v2 = emb[(size_t)s2 * HIDDEN + lane];
            const float v3 = emb[(size_t)s3 * HIDDEN + lane];
            acc += (v0 + v1) + (v2 + v3);
        }
        for (; c < m; ++c)
            acc += emb[(size_t)slots[base + c] * HIDDEN + lane];
        msg_c[(size_t)i * HIDDEN + lane] = acc;
    }
}

// ---------------------------------------------------------------------------
// Head: x = msg_c[inv[post[p]]]; h = relu(x @ Wc + bc); out = sigmoid(h.Wo+bo)
// ---------------------------------------------------------------------------
__global__ __launch_bounds__(64) void k_head(
    const int* __restrict__ post, const int* __restrict__ inv,
    const float* __restrict__ msg_c,
    const float* __restrict__ Wc, const float* __restrict__ bc,
    const float* __restrict__ Wo, const float* __restrict__ bo,
    float* __restrict__ out, int n_posts)
{
    const int lane = threadIdx.x;
    float w[HIDDEN];
    #pragma unroll
    for (int k = 0; k < HIDDEN; ++k) w[k] = Wc[k * HIDDEN + lane];
    const float bias = bc[lane];
    const float wo   = Wo[lane];
    const float bo_s = bo[0];

    for (int p = blockIdx.x; p < n_posts; p += gridDim.x) {
        const int n = post[p];
        const int i = inv[n];
        const float4* __restrict__ row = (const float4*)(msg_c + (size_t)i * HIDDEN);
        float acc0 = 0.f, acc1 = 0.f, acc2 = 0.f, acc3 = 0.f;
        #pragma unroll
        for (int k4 = 0; k4 < HIDDEN / 4; ++k4) {
            const float4 a = row[k4];
            acc0 = fmaf(a.x, w[4 * k4 + 0], acc0);
            acc1 = fmaf(a.y, w[4 * k4 + 1], acc1);
            acc2 = fmaf(a.z, w[4 * k4 + 2], acc2);
            acc3 = fmaf(a.w, w[4 * k4 + 3], acc3);
        }
        const float h = fmaxf((acc0 + acc1) + (acc2 + acc3) + bias, 0.0f);

        float c = h * wo;
        #pragma unroll
        for (int off = 32; off > 0; off >>= 1)
            c += __shfl_down(c, off);
        if (lane == 0)
            out[p] = 1.0f / (1.0f + __expf(-(c + bo_s)));
    }
}

extern "C" void kernel_launch(void* const* d_in, const int* in_sizes, int n_in,
                              void* d_out, int out_size, void* d_ws, size_t ws_size,
                              hipStream_t stream) {
    const float* A    = (const float*)d_in[0];
    const int*   ei   = (const int*)  d_in[1];
    const int*   post = (const int*)  d_in[2];
    const float* We   = (const float*)d_in[3];
    const float* be   = (const float*)d_in[4];
    const float* Wc   = (const float*)d_in[5];
    const float* bc   = (const float*)d_in[6];
    const float* Wo   = (const float*)d_in[7];
    const float* bo   = (const float*)d_in[8];
    float* out = (float*)d_out;

    const int n_nodes = in_sizes[0] / NODE_DIM;   // 100000
    const int n_edges = in_sizes[1] / 2;          // 1200000
    const int n_posts = in_sizes[2];              // 50000

    // ---- workspace layout (all regions written before read; ~45.7 MB) ----
    char* p = (char*)d_ws;
    float* emb      = (float*)p;              p += (size_t)n_nodes * HIDDEN * 4;  // 25.6 MB
    float* msg_c    = (float*)p;              p += (size_t)n_posts * HIDDEN * 4;  // 12.8 MB (compacted)
    int*   slots    = (int*)p;                p += (size_t)n_edges * 4;           // 4.8 MB
    int*   flag     = (int*)p;                p += (size_t)n_nodes * 4;           // zeroed
    int*   count    = (int*)p;                p += (size_t)n_nodes * 4;           // zeroed
    int*   listCnt  = (int*)p;                p += 256;                           // zeroed
    int*   row_start= (int*)p;                p += (size_t)n_nodes * 4;
    int*   cursor   = (int*)p;                p += (size_t)n_nodes * 4;
    int*   nodelist = (int*)p;                p += (size_t)n_nodes * 4;
    int*   inv      = (int*)p;                p += (size_t)n_nodes * 4;
    int*   blockSums= (int*)p;                p += 512;
    int*   blockBase= (int*)p;                p += 512;

    const int* srcs = ei;
    const int* dsts = ei + n_edges;
    const int nb = (n_nodes + SCAN_CHUNK - 1) / SCAN_CHUNK;   // 98 <= 128
    const int n_tiles = n_nodes / 16;
    const int rem     = n_nodes - n_tiles * 16;

    // flag, count, listCnt are contiguous -> single memset
    hipMemsetAsync(flag, 0, (size_t)n_nodes * 8 + 256, stream);
    k_setflags<<<(n_posts + 255) / 256, 256, 0, stream>>>(post, flag, nodelist, inv, listCnt, n_posts);
    k_encode_mfma<<<1024, 256, 0, stream>>>(A, We, be, emb, n_tiles);
    if (rem > 0)
        k_encode_tail<<<rem, 64, 0, stream>>>(A, We, be, emb, n_tiles * 16);
    k_count<<<4096, 256, 0, stream>>>(dsts, flag, count, n_edges);
    k_scan1<<<nb, 256, 0, stream>>>(count, row_start, blockSums, n_nodes);
    k_scan2<<<1, 128, 0, stream>>>(blockSums, blockBase, nb);
    k_scan3<<<(n_nodes + 255) / 256, 256, 0, stream>>>(row_start, blockBase, cursor, n_nodes);
    k_fill<<<4096, 256, 0, stream>>>(srcs, dsts, flag, cursor, slots, n_edges);
    k_gather<<<6144, 256, 0, stream>>>(nodelist, listCnt, row_start, count, slots, emb, msg_c);
    k_head<<<4096, 64, 0, stream>>>(post, inv, msg_c, Wc, bc, Wo, bo, out, n_posts);
}